// Round 5
// baseline (182.613 us; speedup 1.0000x reference)
//
#include <hip/hip_runtime.h>
#include <math.h>

// SemiConnectedConv as dense bf16-MFMA implicit GEMM, 3 kernels:
//  1) prep_wfrag:  weights -> dense zero-padded MFMA B-fragments (26.6 KB ws)
//  2) transpose_x: fp32 NCHW -> bf16 NHWC with 2-px zero halo (26.6 MB ws)
//  3) semiconv_main: per (h,b): stage 5 contiguous xT rows via global_load_lds,
//     13 K-step MFMA (26 taps x 16ch; tap 25 aliases tap 0 with zero weights),
//     sigmoid epilogue with float4 full-line stores.

#define HH 224
#define WW 224
#define BB 16
#define CIN 16
#define NBR 32
#define PH 228
#define PW 228
#define KSTEPS 13

typedef short short8 __attribute__((ext_vector_type(8)));
typedef float f32x4 __attribute__((ext_vector_type(4)));

static __device__ __forceinline__ unsigned short f2bf(float f) {
    unsigned int u = __float_as_uint(f);
    return (unsigned short)((u + 0x7FFFu + ((u >> 16) & 1u)) >> 16);   // RNE
}

// ---- weights -> B-fragments: short bfrag[KSTEPS][2 nt][64 lane][8] ----
__global__ __launch_bounds__(64)
void prep_wfrag(const float* __restrict__ Wc, short* __restrict__ ws) {
    int t = blockIdx.x * 64 + threadIdx.x;   // 26 blocks x 64
    int lane = t & 63;
    int rest = t >> 6;
    int nt = rest & 1;
    int kstep = rest >> 1;
    int n = lane & 15;
    int bi = nt * 16 + n;
    int kbase = kstep * 32 + (lane >> 4) * 8;
    short8 pack;
    #pragma unroll
    for (int j = 0; j < 8; ++j) {
        int kg = kbase + j;
        float val = 0.0f;
        if (kg < 400) {
            int tap = kg >> 4;
            int c = kg & 15;
            if (((c + bi) & 15) < 8) {
                int jsel = 0;
                for (int cc = 0; cc < c; ++cc) jsel += (((cc + bi) & 15) < 8) ? 1 : 0;
                val = Wc[(bi * 8 + jsel) * 25 + tap];
            }
        }
        pack[j] = (short)f2bf(val);
    }
    *(short8*)(ws + (size_t)t * 8) = pack;
}

// ---- x fp32 NCHW -> xT bf16 [b][ph 228][pw 228][c 16], zero halo ----
__global__ __launch_bounds__(256)
void transpose_x(const float* __restrict__ x, short* __restrict__ xT) {
    const int b = blockIdx.y;
    const int prow = blockIdx.x * 4 + (threadIdx.x >> 6);   // 0..227
    const int t = threadIdx.x & 63;
    const int gh = prow - 2;
    short* dst = xT + ((size_t)b * PH + prow) * (PW * CIN);

    if (t < 56) {
        const int gw = t * 4;                 // -> padded cols 4t+2..4t+5
        unsigned int pk[4][8];
        if ((unsigned)gh < HH) {
            const float* xp = x + (size_t)b * CIN * HH * WW + (size_t)gh * WW + gw;
            #pragma unroll
            for (int w2 = 0; w2 < 8; ++w2) {  // channel pair (2*w2, 2*w2+1)
                float4 v0 = *(const float4*)(xp + (size_t)(2 * w2) * (HH * WW));
                float4 v1 = *(const float4*)(xp + (size_t)(2 * w2 + 1) * (HH * WW));
                const float* f0 = (const float*)&v0;
                const float* f1 = (const float*)&v1;
                #pragma unroll
                for (int p = 0; p < 4; ++p)
                    pk[p][w2] = (unsigned)f2bf(f0[p]) | ((unsigned)f2bf(f1[p]) << 16);
            }
        } else {
            #pragma unroll
            for (int p = 0; p < 4; ++p)
                #pragma unroll
                for (int w2 = 0; w2 < 8; ++w2) pk[p][w2] = 0u;
        }
        #pragma unroll
        for (int p = 0; p < 4; ++p) {
            int4* o = (int4*)(dst + (size_t)(gw + 2 + p) * CIN);
            o[0] = make_int4(pk[p][0], pk[p][1], pk[p][2], pk[p][3]);
            o[1] = make_int4(pk[p][4], pk[p][5], pk[p][6], pk[p][7]);
        }
    } else if (t == 56) {                     // halo cols {0,1} and {226,227}
        int4 z = make_int4(0, 0, 0, 0);
        int4* o0 = (int4*)(dst);
        o0[0] = z; o0[1] = z;
        int4* o1 = (int4*)(dst + 226 * CIN);
        o1[0] = z; o1[1] = z;
    }
}

// ---- main: block = (h row, batch), 7 waves, wave = 32 pixels x 32 branches --
__global__ __launch_bounds__(448)
void semiconv_main(const short* __restrict__ xT,
                   const short* __restrict__ wfrag,
                   const float* __restrict__ bc,
                   float* __restrict__ out) {
    __shared__ short tile[5 * PW * CIN];      // 36480 B, contiguous copy of xT

    const int bidx = blockIdx.x;
    const int b = blockIdx.y;
    const int h = (bidx & 7) * 28 + (bidx >> 3);   // XCD-contiguous bands
    const int tid = threadIdx.x;
    const int wave = tid >> 6;
    const int lane = tid & 63;

    // 5 padded rows h..h+4 are ONE contiguous span: 2280 x 16B chunks
    const short* src0 = xT + ((size_t)b * PH + h) * (PW * CIN);
    #pragma unroll
    for (int i = 0; i < 5; ++i) {
        __builtin_amdgcn_global_load_lds(
            (const __attribute__((address_space(1))) void*)(src0 + (size_t)(tid + i * 448) * 8),
            (__attribute__((address_space(3))) void*)(tile + (wave * 64 + i * 448) * 8),
            16, 0, 0);
    }
    if (tid < 40) {                            // tail chunks 2240..2279
        const int chunk = 2240 + tid;
        *(int4*)(tile + chunk * 8) = *(const int4*)(src0 + (size_t)chunk * 8);
    }
    __syncthreads();

    const int m = lane & 15;
    const int c0 = ((lane >> 4) & 1) * 8;
    const int half = lane >> 5;
    const int wbase = wave * 32;
    const int baseA = (wbase + m) * CIN + c0;

    f32x4 acc[2][2] = {};
    const short8* wfv = (const short8*)wfrag;

    #pragma unroll
    for (int k = 0; k < KSTEPS; ++k) {
        const int tA = 2 * k, tB = 2 * k + 1;
        const int offA = (tA / 5) * (PW * CIN) + (tA % 5) * CIN;
        const int offB = (tB < 25) ? (tB / 5) * (PW * CIN) + (tB % 5) * CIN
                                   : offA;     // pad tap: weights are zero
        const int tapoff = half ? offB : offA;
        short8 b0 = wfv[(k * 2 + 0) * 64 + lane];
        short8 b1 = wfv[(k * 2 + 1) * 64 + lane];
        #pragma unroll
        for (int mt = 0; mt < 2; ++mt) {
            short8 a = *(const short8*)&tile[tapoff + baseA + mt * 16 * CIN];
            acc[mt][0] = __builtin_amdgcn_mfma_f32_16x16x32_bf16(a, b0, acc[mt][0], 0, 0, 0);
            acc[mt][1] = __builtin_amdgcn_mfma_f32_16x16x32_bf16(a, b1, acc[mt][1], 0, 0, 0);
        }
    }

    // epilogue: D col = branch (lane&15), row = pixel (lane>>4)*4 + reg
    const int rowm = (lane >> 4) * 4;
    #pragma unroll
    for (int nt = 0; nt < 2; ++nt) {
        const int branch = nt * 16 + m;
        const float bias = bc[branch];
        #pragma unroll
        for (int mt = 0; mt < 2; ++mt) {
            const int w = wbase + mt * 16 + rowm;
            float4 v;
            v.x = __builtin_amdgcn_rcpf(1.0f + __expf(-(acc[mt][nt][0] + bias)));
            v.y = __builtin_amdgcn_rcpf(1.0f + __expf(-(acc[mt][nt][1] + bias)));
            v.z = __builtin_amdgcn_rcpf(1.0f + __expf(-(acc[mt][nt][2] + bias)));
            v.w = __builtin_amdgcn_rcpf(1.0f + __expf(-(acc[mt][nt][3] + bias)));
            *(float4*)(out + (((size_t)b * NBR + branch) * HH + h) * WW + w) = v;
        }
    }
}

extern "C" void kernel_launch(void* const* d_in, const int* in_sizes, int n_in,
                              void* d_out, int out_size, void* d_ws, size_t ws_size,
                              hipStream_t stream) {
    const float* x  = (const float*)d_in[0];
    const float* Wc = (const float*)d_in[1];
    const float* bc = (const float*)d_in[2];
    float* out = (float*)d_out;

    short* wfrag = (short*)d_ws;                         // 26,624 B
    short* xT    = (short*)((char*)d_ws + 32768);        // 26,615,808 B

    prep_wfrag<<<26, 64, 0, stream>>>(Wc, wfrag);
    transpose_x<<<dim3(57, 16), 256, 0, stream>>>(x, xT);
    semiconv_main<<<dim3(224, 16), 448, 0, stream>>>(xT, wfrag, bc, out);
}